// Round 4
// baseline (509.885 us; speedup 1.0000x reference)
//
#include <hip/hip_runtime.h>
#include <stdint.h>
#include <math.h>

#define NTOK (1024 * 256)   // B*L
#define TPB_A 128           // tokens per kA block
#define GRID_B 2048         // kB blocks (tile-stride loop)
#define P_DIM 300
#define P_PAD 320           // padded K for MFMA (multiple of 32)
#define P_LDS 328           // LDS row stride in bf16 elems (656B rows, 16B-aligned)
#define E_DIM 256

typedef __attribute__((ext_vector_type(8))) short bf16x8_t;
typedef __attribute__((ext_vector_type(4))) float f32x4_t;

__device__ __forceinline__ unsigned short f2b(float f) {
    union { float f; unsigned int i; } v; v.f = f;
    unsigned int x = v.i;
    return (unsigned short)((x + 0x7FFFu + ((x >> 16) & 1u)) >> 16);  // RNE f32->bf16
}

// kA: classify + global compaction + regular-row copy + lin_w convert.
//  - 128 tokens/block, 256 thr. Threads 0..127 classify (x, v2c, v2r gathers),
//    ballot-compact into global (list_t, list_cm) with ONE atomicAdd per block.
//  - copy: wave w owns tokens w*32..w*32+31. Row index ri from LDS; custom
//    tokens have ri=-1 -> load row 0 (cached zeros) so all 8 loads issue
//    branch-free; store is predicated (custom rows written later by kB).
//  - nt stores: out is write-once; keep gather tables resident in L2/L3.
__global__ __launch_bounds__(256) void kA_copy(
        const int* __restrict__ x, const int* __restrict__ v2c,
        const int* __restrict__ v2r,
        const float* __restrict__ regular_w, const float* __restrict__ lin_b,
        const float* __restrict__ lin_w, unsigned short* __restrict__ lin_w_pad,
        int* __restrict__ list_t, int* __restrict__ list_cm,
        int* __restrict__ counter,
        float* __restrict__ out) {
    __shared__ int s_ri[TPB_A];
    __shared__ int wb[2];
    int tid  = threadIdx.x;
    int wid  = tid >> 6;
    int lane = tid & 63;

    // fused convert+pad lin_w f32[256,300] -> bf16[256,320] (first 320 blocks)
    if (blockIdx.x < (E_DIM * P_PAD) / 256) {
        int idx = blockIdx.x * 256 + tid;
        int e = idx / P_PAD;
        int k = idx - e * P_PAD;
        lin_w_pad[idx] = (k < P_DIM) ? f2b(lin_w[(size_t)e * P_DIM + k])
                                     : (unsigned short)0;
    }

    int base = blockIdx.x * TPB_A;
    int cm = 0;
    unsigned long long bl = 0;
    if (tid < TPB_A) {                       // waves 0,1 full; waves 2,3 skip
        int xv = x[base + tid];
        cm = v2c[xv];                        // custom table idx, 0 if regular
        int rv = v2r[xv];                    // regular idx (0 for custom vocab)
        s_ri[tid] = (cm > 0) ? -1 : rv;      // -1 marks custom
        bl = __ballot(cm > 0);
        if (lane == 0) wb[wid] = __popcll(bl);
    }
    __syncthreads();
    if (tid == 0) {
        int tot = wb[0] + wb[1];
        int b0 = atomicAdd(counter, tot);    // the ONLY global atomic per block
        int c0 = wb[0];
        wb[0] = b0; wb[1] = b0 + c0;
    }
    __syncthreads();
    if (tid < TPB_A && cm > 0) {
        int pos = wb[wid] + __popcll(bl & ((1ull << lane) - 1ull));
        list_t[pos]  = base + tid;
        list_cm[pos] = cm;
    }

    // ---- copy phase: 32 rows per wave, 8 loads in flight, branch-free loads ----
    f32x4_t lb4 = *(const f32x4_t*)(lin_b + lane * 4);
    int tbase = base + wid * 32;
    #pragma unroll 1
    for (int it0 = 0; it0 < 32; it0 += 8) {
        int ris[8];
        f32x4_t rows[8];
        #pragma unroll
        for (int u = 0; u < 8; u++) ris[u] = s_ri[wid * 32 + it0 + u];
        #pragma unroll
        for (int u = 0; u < 8; u++) {
            int r = (ris[u] < 0) ? 0 : ris[u];   // custom -> row 0 (cached zeros)
            rows[u] = *(const f32x4_t*)(regular_w + (size_t)r * E_DIM + lane * 4);
        }
        #pragma unroll
        for (int u = 0; u < 8; u++) {
            if (ris[u] >= 0) {                   // wave-uniform predicate
                f32x4_t o = rows[u] + lb4;
                __builtin_nontemporal_store(
                    o, (f32x4_t*)(out + (size_t)(tbase + it0 + u) * E_DIM + lane * 4));
            }
        }
    }
}

// kB: custom tokens from the globally-compacted list. Full 32-row MFMA tiles.
// 2048 blocks, tile-stride loop (expected ~1639 tiles for ~52K custom tokens).
__global__ __launch_bounds__(256) void kB_custom(
        const int* __restrict__ list_t, const int* __restrict__ list_cm,
        const int* __restrict__ counter,
        const float* __restrict__ fixed_w,
        const float* __restrict__ train_w,
        const unsigned short* __restrict__ lin_w_pad,
        const float* __restrict__ regular_w,
        const int* __restrict__ v2r, const float* __restrict__ lin_b,
        float* __restrict__ out) {
    __shared__ __align__(16) unsigned short semb[32][P_LDS];
    int count = counter[0];
    if ((int)(blockIdx.x * 32) >= count) return;   // block-uniform, before syncs

    int tid  = threadIdx.x;
    int wid  = tid >> 6;
    int lane = tid & 63;
    int col   = lane & 15;
    int kgrp  = lane >> 4;
    int e0w   = wid * 64;
    int rbase = kgrp * 4;                 // C/D: col = lane&15, row = kgrp*4 + reg

    float lbe[4], rr0[4];
    int rid0 = v2r[0];
    const float* rrow0 = regular_w + (size_t)rid0 * E_DIM;   // zeros (pad row)
    #pragma unroll
    for (int nt = 0; nt < 4; nt++) {
        lbe[nt] = lin_b[e0w + nt * 16 + col];
        rr0[nt] = rrow0[e0w + nt * 16 + col];
    }

    for (int i0 = blockIdx.x * 32; i0 < count; i0 += gridDim.x * 32) {
        int cn = count - i0; if (cn > 32) cn = 32;

        // Phase 1: Poincare embeddings -> bf16 LDS rows (wave-strided)
        for (int i = wid; i < cn; i += 4) {
            int cm = list_cm[i0 + i];
            const float* fw = fixed_w + (size_t)cm * P_DIM;
            const float* tw = train_w + (size_t)cm * P_DIM;
            float w[5], tr[5];
            float sw2 = 0.f, st2 = 0.f, swt = 0.f;
            #pragma unroll
            for (int s = 0; s < 5; s++) {
                int j = lane + 64 * s;
                float wv = 0.f, tv = 0.f;
                if (j < P_DIM) { wv = fw[j]; tv = tw[j]; }
                w[s] = wv; tr[s] = tv;
                sw2 = fmaf(wv, wv, sw2); st2 = fmaf(tv, tv, st2); swt = fmaf(wv, tv, swt);
            }
            #pragma unroll
            for (int m = 32; m >= 1; m >>= 1) {
                sw2 += __shfl_xor(sw2, m, 64);
                st2 += __shfl_xor(st2, m, 64);
                swt += __shfl_xor(swt, m, 64);
            }
            float norm = sqrtf(sw2);
            norm = fminf(norm, 0.9999999f);
            float scale = (norm > 0.f) ? (atanhf(norm) / norm) : 1.0f;
            float x2 = scale * scale * sw2;      // ||logmap0(w)||^2
            float y2 = st2;
            float xy = scale * swt;              // <logmap0(w), tr>
            float c1 = (1.f + 2.f * xy + y2) * scale;
            float c2 = (1.f - x2);
            float den = fmaxf(1.f + 2.f * xy + x2 * y2, 1e-15f);
            float inv = 1.f / den;
            #pragma unroll
            for (int s = 0; s < 5; s++) {
                int j = lane + 64 * s;           // covers 0..319
                float v = (j < P_DIM) ? (c1 * w[s] + c2 * tr[s]) * inv : 0.f;
                semb[i][j] = f2b(v);
            }
        }
        __syncthreads();

        // Phase 2: 32x256 MFMA tile (rows >= cn are garbage; masked at store;
        // MFMA rows are independent so garbage cannot cross rows)
        f32x4_t acc[2][4];
        #pragma unroll
        for (int a = 0; a < 2; a++)
            #pragma unroll
            for (int b = 0; b < 4; b++) acc[a][b] = (f32x4_t)(0.f);

        #pragma unroll
        for (int kk = 0; kk < 10; kk++) {
            int k0 = kk * 32 + kgrp * 8;
            bf16x8_t afr[2], bfr[4];
            afr[0] = *(const bf16x8_t*)(&semb[col][k0]);
            afr[1] = *(const bf16x8_t*)(&semb[16 + col][k0]);
            #pragma unroll
            for (int nt = 0; nt < 4; nt++) {
                int e = e0w + nt * 16 + col;
                bfr[nt] = *(const bf16x8_t*)(lin_w_pad + (size_t)e * P_PAD + k0);
            }
            #pragma unroll
            for (int mt = 0; mt < 2; mt++)
                #pragma unroll
                for (int nt = 0; nt < 4; nt++)
                    acc[mt][nt] = __builtin_amdgcn_mfma_f32_16x16x32_bf16(
                        afr[mt], bfr[nt], acc[mt][nt], 0, 0, 0);
        }

        // epilogue: + lin_b + regular_w[v2r[0]] (zeros, kept for exactness)
        #pragma unroll
        for (int mt = 0; mt < 2; mt++) {
            #pragma unroll
            for (int r = 0; r < 4; r++) {
                int row = mt * 16 + rbase + r;
                if (row < cn) {
                    int t = list_t[i0 + row];
                    float* orow = out + (size_t)t * E_DIM;
                    #pragma unroll
                    for (int nt = 0; nt < 4; nt++) {
                        __builtin_nontemporal_store(
                            acc[mt][nt][r] + lbe[nt] + rr0[nt],
                            orow + e0w + nt * 16 + col);
                    }
                }
            }
        }
        __syncthreads();   // semb reuse by next tile
    }
}

extern "C" void kernel_launch(void* const* d_in, const int* in_sizes, int n_in,
                              void* d_out, int out_size, void* d_ws, size_t ws_size,
                              hipStream_t stream) {
    const int* x   = (const int*)d_in[0];
    // d_in[1] = custom_indices (unused; vocab_to_custom[x]!=0 is equivalent to isin)
    const int* v2c = (const int*)d_in[2];
    const int* v2r = (const int*)d_in[3];
    const float* fixed_w   = (const float*)d_in[4];
    const float* train_w   = (const float*)d_in[5];
    const float* regular_w = (const float*)d_in[6];
    const float* lin_w     = (const float*)d_in[7];
    const float* lin_b     = (const float*)d_in[8];
    float* out = (float*)d_out;

    // ws layout (~2.3 MB): [counter 256B][list_t 1MB][list_cm 1MB][lin_w_pad 160KB]
    char* ws = (char*)d_ws;
    int* counter = (int*)ws;
    int* list_t  = (int*)(ws + 256);
    int* list_cm = (int*)(ws + 256 + 4 * (size_t)NTOK);
    unsigned short* lin_w_pad = (unsigned short*)(ws + 256 + 8 * (size_t)NTOK);

    hipMemsetAsync(counter, 0, 64, stream);
    kA_copy<<<NTOK / TPB_A, 256, 0, stream>>>(x, v2c, v2r, regular_w, lin_b,
                                              lin_w, lin_w_pad,
                                              list_t, list_cm, counter, out);
    kB_custom<<<GRID_B, 256, 0, stream>>>(list_t, list_cm, counter,
                                          fixed_w, train_w, lin_w_pad,
                                          regular_w, v2r, lin_b, out);
}